// Round 12
// baseline (34.629 us; speedup 1.0000x reference)
//
#include <hip/hip_runtime.h>
#include <hip/hip_bf16.h>
#include <float.h>

// Problem constants
#define BATCH 8
#define CHN   64
#define HW    56
#define PIX   3136          // 56*56
#define BP    25088         // BATCH*PIX (dots plane size, doubles)
#define LDB   72            // band LDS stride in bf16 elems (144 B, 16-B aligned)
#define TS    66            // dots tile stride in floats (EVEN: float2 LDS reads need 8B align)
#define QW    14            // pixels per dots block (quarter row)
#define QC    18            // tile cols (QW + 4 halo)
#define NLOC  54            // 3 rows x 18 cols

typedef __bf16 bf16x8 __attribute__((ext_vector_type(8)));
typedef float  f32x4  __attribute__((ext_vector_type(4)));

static __device__ __forceinline__ unsigned short f2bf(float f) {
    unsigned int u = __float_as_uint(f);
    u += 0x7fffu + ((u >> 16) & 1u);          // round-to-nearest-even
    return (unsigned short)(u >> 16);
}

// ---------------------------------------------------------------------------
// Stage 1: dots[s][b][p] — byte-identical to R20/R23/R24/R26.
// Budget (R19/R25): T_dots ~= 8.25 us, T_fused ~= 9.5 us, rest overhead.
// ---------------------------------------------------------------------------
__global__ __launch_bounds__(256) void dots_kernel(const float* __restrict__ x,
                                                   const float* __restrict__ w,
                                                   double* __restrict__ dots,
                                                   double* __restrict__ invn,
                                                   unsigned short* __restrict__ wbf,
                                                   unsigned short* __restrict__ xT) {
    const int blk = blockIdx.x;
    const int t = threadIdx.x;
    if (blk >= 1792) {                            // 16 tail blocks: pack wbf
        int wi = (blk - 1792) * 256 + t;          // 0..4095
        #pragma unroll
        for (int k = 0; k < 9; k++) {
            int l = wi + k * 4096;                // l = (o*9+tap)*64 + c
            int otap = l >> 6, c = l & 63;
            int o = otap / 9, tap = otap - o * 9;
            wbf[l] = f2bf(w[(o * CHN + c) * 9 + tap]);
        }
        return;
    }
    const int quarter = blk & 3;
    const int r = (blk >> 2) % HW;
    const int b = blk / 224;
    const int jbase = quarter * QW;

    __shared__ float tile[NLOC * TS];             // 14.3 KB
    // R20 staging: float2 pairs, shift-based indexing (pair guard exact).
    {
        const int c = t >> 2;                     // 0..63
        const int q4 = t & 3;
        const float* xc = x + (size_t)b * CHN * PIX + (size_t)c * PIX;
        #pragma unroll
        for (int it = 0; it < 7; it++) {
            int p2 = q4 + it * 4;                 // 0..27 (27 = skip)
            if (p2 < 27) {
                int lr = p2 / 9;                  // tile row 0..2
                int lc = (p2 - lr * 9) * 2;       // 0,2,..,16
                int row = r - 2 + lr;
                int col = jbase - 2 + lc;
                float2 v = {0.0f, 0.0f};
                if (row >= 0 && row < HW && col >= 0 && col < HW)
                    v = *(const float2*)(xc + row * HW + col);
                int rem = lr * QC + lc;
                tile[rem * TS + c] = v.x;
                tile[(rem + 1) * TS + c] = v.y;
            }
        }
    }
    __syncthreads();

    // xT emit: t<224: jl = t>>4 (0..13), oct = t&15 -> 4 channels
    if (t < 224) {
        const int jl = t >> 4, oct = t & 15;
        const float* src = &tile[(2 * QC + 2 + jl) * TS + oct * 4];
        float2 f0 = *(const float2*)(src);
        float2 f1 = *(const float2*)(src + 2);
        uint2 pk;
        pk.x = (unsigned int)f2bf(f0.x) | ((unsigned int)f2bf(f0.y) << 16);
        pk.y = (unsigned int)f2bf(f1.x) | ((unsigned int)f2bf(f1.y) << 16);
        *(uint2*)(xT + ((size_t)b * PIX + r * HW + jbase + jl) * CHN + oct * 4) = pk;
    }

    if (t >= 182) return;
    const int s = t / QW;                         // 0..12
    const int jl = t - s * QW;                    // local col 0..13
    const int lr = s / 5;                         // dr = lr-2 in {-2,-1,0}
    const int dc = s % 5 - 2;
    const float* ctr = &tile[(2 * QC + 2 + jl) * TS];
    const float* nbr = &tile[(lr * QC + jl + dc + 2) * TS];

    double acc = 0.0;
    #pragma unroll 8
    for (int k = 0; k < 32; k++) {
        float2 cv = *(const float2*)(ctr + 2 * k);
        float2 nv = *(const float2*)(nbr + 2 * k);
        acc += (double)cv.x * (double)nv.x;       // c = 2k
        acc += (double)cv.y * (double)nv.y;       // c = 2k+1 (sequential order kept)
    }
    const int p = r * HW + jbase + jl;
    dots[(size_t)s * BP + b * PIX + p] = acc;     // plane-major: coalesced in jl
    if (s == 12) invn[(size_t)b * PIX + p] = 1.0 / sqrt(acc);
}

// ---------------------------------------------------------------------------
// Stage 2 (fused select + gather-conv), per (b, image row r).
// R26 was exactly neutral -> VGPR-budget theory dead; by elimination
// (R23 fixed loads, R24 proved MFMA phase off-path), the select wave's
// SERIAL chain is the barrier-critical term: 9-rank rescan = 225 DEPENDENT
// fp64 compare steps (~2-3.5K cy latency) + 36-step bubble sort, during
// which the other 3 waves wait and the CU (1.75 blocks) has nothing to run.
// R27 SINGLE CHANGE: dependency-free stable RANK-SELECT.
//  * 300 independent pairwise compares (u<s): k2[u]<=k2[s] -> rank[s]++
//    else rank[u]++. Stable ranks = permutation of 0..24; selected =
//    rank<9 — exactly the rescan's strict-< earliest-index-tie-break set
//    (incl. +-0.0 and DBL_MAX ties).
//  * sort eliminated: q is monotone in s (row-major window), so ascending-s
//    emission of selected entries IS ascending-q; slot = popcount(mask<s).
// Same selected set, same qtab -> bit-identical output. All else identical.
// ---------------------------------------------------------------------------
__global__ __launch_bounds__(256, 2) void fused_kernel(const unsigned short* __restrict__ xT,
                                                       const double* __restrict__ dots,
                                                       const double* __restrict__ invn,
                                                       const unsigned short* __restrict__ wbf,
                                                       float* __restrict__ out) {
    const int b = blockIdx.y;
    const int r = blockIdx.x;
    __shared__ unsigned short band[300 * LDB];
    __shared__ int qtab[9 * 64];
    const int t = threadIdx.x;

    const int wv = t >> 6, ln = t & 63;
    const int mrow = ln & 15, kq = ln >> 4;
    const int o = wv * 16 + mrow;

    if (t < 56) {
        const int jj = t;
        const int bp = b * PIX;
        const int p0 = r * HW + jj;
        const double* inb = invn + bp;

        // Phase A: pure loads into registers — all 50 issued before any use.
        double rawv[25], invv[25];
        #pragma unroll
        for (int s = 0; s < 25; s++) {
            int dr = s / 5 - 2, dc = s % 5 - 2;
            int qi = r + dr, qj = jj + dc;
            bool valid = qi >= 0 && qi < HW && qj >= 0 && qj < HW;
            int qc = valid ? qi * HW + qj : p0;   // clamped: always in-bounds
            rawv[s] = (s < 13) ? dots[(size_t)s * BP + bp + p0]
                               : dots[(size_t)(24 - s) * BP + bp + qc];
            invv[s] = inb[qc];
        }
        // Phase B: keys (invalid -> DBL_MAX mask; same values as R20).
        double k2[25];
        #pragma unroll
        for (int s = 0; s < 25; s++) {
            int dr = s / 5 - 2, dc = s % 5 - 2;
            int qi = r + dr, qj = jj + dc;
            bool valid = qi >= 0 && qi < HW && qj >= 0 && qj < HW;
            k2[s] = valid ? rawv[s] * invv[s] : DBL_MAX;
        }
        // Phase C: stable ranks — 300 independent compares, no serial chain.
        int rank[25];
        #pragma unroll
        for (int s = 0; s < 25; s++) rank[s] = 0;
        #pragma unroll
        for (int s = 1; s < 25; s++) {
            #pragma unroll
            for (int u = 0; u < s; u++) {
                bool le = (k2[u] <= k2[s]);       // u<s: u wins ties (stable)
                rank[s] += le ? 1 : 0;
                rank[u] += le ? 0 : 1;
            }
        }
        // Phase D: selection mask; emit in ascending s == ascending q.
        unsigned int m = 0u;
        #pragma unroll
        for (int s = 0; s < 25; s++)
            m |= (rank[s] < 9 ? 1u : 0u) << s;
        #pragma unroll
        for (int s = 0; s < 25; s++) {
            if ((m >> s) & 1u) {
                int slot = __popc(m & ((1u << s) - 1u));
                // qi-r+2 = s/5, qj+2 = jj + s%5  (no division by HW needed)
                qtab[slot * 64 + jj] = ((s / 5) * 60 + (jj + s % 5)) * LDB;
            }
        }
    } else if (t < 64) {
        #pragma unroll
        for (int k = 0; k < 9; k++) qtab[k * 64 + t] = 0;   // tail dummy
    } else {
        // band staging: 2400 uint4 items over 192 threads = 12 or 13 each.
        // R23: compile-time unroll — all loads issued, then all ds_writes.
        const int l0 = t - 64;                    // 0..191
        uint4 v[13];
        #pragma unroll
        for (int it = 0; it < 13; it++) {
            int l = l0 + it * 192;
            v[it] = (uint4){0, 0, 0, 0};
            if (l < 2400) {
                int local = l >> 3, ch8 = l & 7;
                int lr = local / 60, col = local - lr * 60 - 2;
                int row = r - 2 + lr;
                if (row >= 0 && row < HW && col >= 0 && col < HW)
                    v[it] = *(const uint4*)(xT + ((size_t)b * PIX + row * HW + col) * CHN + ch8 * 8);
            }
        }
        #pragma unroll
        for (int it = 0; it < 13; it++) {
            int l = l0 + it * 192;
            if (l < 2400) {
                int local = l >> 3, ch8 = l & 7;
                *(uint4*)(&band[local * LDB + ch8 * 8]) = v[it];
            }
        }
    }
    __syncthreads();

    // R24: eager post-barrier hoists — A-fragments (18 x b128) and qtab
    // indices (36 x b32) batched before the tap loop; loop fully unrolled.
    bf16x8 afr[9][2];
    const unsigned short* wbase = wbf + (size_t)o * 9 * 64 + kq * 8;
    #pragma unroll
    for (int tap = 0; tap < 9; tap++) {
        afr[tap][0] = *(const bf16x8*)(wbase + tap * 64);
        afr[tap][1] = *(const bf16x8*)(wbase + tap * 64 + 32);
    }
    int qv[9][4];
    #pragma unroll
    for (int tap = 0; tap < 9; tap++) {
        #pragma unroll
        for (int nt = 0; nt < 4; nt++)
            qv[tap][nt] = qtab[tap * 64 + nt * 16 + mrow];
    }

    f32x4 oacc[4] = {{0,0,0,0},{0,0,0,0},{0,0,0,0},{0,0,0,0}};
    #pragma unroll
    for (int tap = 0; tap < 9; tap++) {
        #pragma unroll
        for (int nt = 0; nt < 4; nt++) {
            const unsigned short* bptr = &band[qv[tap][nt] + kq * 8];
            bf16x8 b0 = *(const bf16x8*)bptr;
            bf16x8 b1 = *(const bf16x8*)(bptr + 32);
            oacc[nt] = __builtin_amdgcn_mfma_f32_16x16x32_bf16(afr[tap][0], b0, oacc[nt], 0, 0, 0);
            oacc[nt] = __builtin_amdgcn_mfma_f32_16x16x32_bf16(afr[tap][1], b1, oacc[nt], 0, 0, 0);
        }
    }
    // C/D: col = lane&15 = p-within-tile, row = kq*4+rg = o-within-strip
    float* ob = out + ((size_t)b * 64 + wv * 16 + kq * 4) * PIX + r * HW;
    #pragma unroll
    for (int nt = 0; nt < 4; nt++) {
        int p = nt * 16 + mrow;
        if (p < HW) {
            #pragma unroll
            for (int rg = 0; rg < 4; rg++) ob[(size_t)rg * PIX + p] = oacc[nt][rg];
        }
    }
}

// ---------------------------------------------------------------------------
// Workspace layout (total ~6.1 MB):
//   dots : 13 * 25088 * 8 = 2,609,152 B @ 0          (plane-major [s][b][p])
//   invn : 25088 * 8      =   200,704 B @ 2,609,152
//   wbf  : 64*9*64 * 2    =    73,728 B @ 2,809,856
//   xT   : 8*3136*64 * 2  = 3,211,264 B @ 2,883,584
// ---------------------------------------------------------------------------
extern "C" void kernel_launch(void* const* d_in, const int* in_sizes, int n_in,
                              void* d_out, int out_size, void* d_ws, size_t ws_size,
                              hipStream_t stream) {
    const float* x = (const float*)d_in[0];
    const float* w = (const float*)d_in[1];
    float* out = (float*)d_out;
    char* ws = (char*)d_ws;
    double*         dots = (double*)ws;
    double*         invn = (double*)(ws + 2609152);
    unsigned short* wbf  = (unsigned short*)(ws + 2809856);
    unsigned short* xT   = (unsigned short*)(ws + 2883584);

    // 1792 blocks cover (b,r,quarter); 16 tail blocks pack wbf
    dots_kernel<<<1808, 256, 0, stream>>>(x, w, dots, invn, wbf, xT);
    fused_kernel<<<dim3(56, 8), 256, 0, stream>>>(xT, dots, invn, wbf, out);
}

// Round 14
// 33.223 us; speedup vs baseline: 1.0423x; 1.0423x over previous
//
#include <hip/hip_runtime.h>
#include <hip/hip_bf16.h>
#include <float.h>

// Problem constants
#define BATCH 8
#define CHN   64
#define HW    56
#define PIX   3136          // 56*56
#define BP    25088         // BATCH*PIX (dots plane size, doubles)
#define LDB   72            // band LDS stride in bf16 elems (144 B, 16-B aligned)
#define TS    66            // dots tile stride in floats (EVEN: float2 LDS reads need 8B align)
#define QW    14            // pixels per dots block (quarter row)
#define QC    18            // tile cols (QW + 4 halo)
#define NLOC  54            // 3 rows x 18 cols

typedef __bf16 bf16x8 __attribute__((ext_vector_type(8)));
typedef float  f32x4  __attribute__((ext_vector_type(4)));

static __device__ __forceinline__ unsigned short f2bf(float f) {
    unsigned int u = __float_as_uint(f);
    u += 0x7fffu + ((u >> 16) & 1u);          // round-to-nearest-even
    return (unsigned short)(u >> 16);
}

// ---------------------------------------------------------------------------
// R29 = byte-exact restore of the verified best (R24/R26, 33.26 us,
// reproduced twice). R28's single-dispatch producer/consumer merge hung the
// GPU (spin-wait + undefined dispatch-order/cross-XCD-visibility assumptions
// — §6 G16 territory) and killed the container; that approach is closed.
// Session budget (measured): dots ~8.25 us (VALU-issue-bound @87% occ),
// fused ~9.5 us (latency-bound; select issue-bound per R27), ~15.5 us
// per-dispatch/fixed overhead outside kernel-source control.
// ---------------------------------------------------------------------------
__global__ __launch_bounds__(256) void dots_kernel(const float* __restrict__ x,
                                                   const float* __restrict__ w,
                                                   double* __restrict__ dots,
                                                   double* __restrict__ invn,
                                                   unsigned short* __restrict__ wbf,
                                                   unsigned short* __restrict__ xT) {
    const int blk = blockIdx.x;
    const int t = threadIdx.x;
    if (blk >= 1792) {                            // 16 tail blocks: pack wbf
        int wi = (blk - 1792) * 256 + t;          // 0..4095
        #pragma unroll
        for (int k = 0; k < 9; k++) {
            int l = wi + k * 4096;                // l = (o*9+tap)*64 + c
            int otap = l >> 6, c = l & 63;
            int o = otap / 9, tap = otap - o * 9;
            wbf[l] = f2bf(w[(o * CHN + c) * 9 + tap]);
        }
        return;
    }
    const int quarter = blk & 3;
    const int r = (blk >> 2) % HW;
    const int b = blk / 224;
    const int jbase = quarter * QW;

    __shared__ float tile[NLOC * TS];             // 14.3 KB
    // R20 staging: float2 pairs, shift-based indexing (pair guard exact).
    {
        const int c = t >> 2;                     // 0..63
        const int q4 = t & 3;
        const float* xc = x + (size_t)b * CHN * PIX + (size_t)c * PIX;
        #pragma unroll
        for (int it = 0; it < 7; it++) {
            int p2 = q4 + it * 4;                 // 0..27 (27 = skip)
            if (p2 < 27) {
                int lr = p2 / 9;                  // tile row 0..2
                int lc = (p2 - lr * 9) * 2;       // 0,2,..,16
                int row = r - 2 + lr;
                int col = jbase - 2 + lc;
                float2 v = {0.0f, 0.0f};
                if (row >= 0 && row < HW && col >= 0 && col < HW)
                    v = *(const float2*)(xc + row * HW + col);
                int rem = lr * QC + lc;
                tile[rem * TS + c] = v.x;
                tile[(rem + 1) * TS + c] = v.y;
            }
        }
    }
    __syncthreads();

    // xT emit: t<224: jl = t>>4 (0..13), oct = t&15 -> 4 channels
    if (t < 224) {
        const int jl = t >> 4, oct = t & 15;
        const float* src = &tile[(2 * QC + 2 + jl) * TS + oct * 4];
        float2 f0 = *(const float2*)(src);
        float2 f1 = *(const float2*)(src + 2);
        uint2 pk;
        pk.x = (unsigned int)f2bf(f0.x) | ((unsigned int)f2bf(f0.y) << 16);
        pk.y = (unsigned int)f2bf(f1.x) | ((unsigned int)f2bf(f1.y) << 16);
        *(uint2*)(xT + ((size_t)b * PIX + r * HW + jbase + jl) * CHN + oct * 4) = pk;
    }

    if (t >= 182) return;
    const int s = t / QW;                         // 0..12
    const int jl = t - s * QW;                    // local col 0..13
    const int lr = s / 5;                         // dr = lr-2 in {-2,-1,0}
    const int dc = s % 5 - 2;
    const float* ctr = &tile[(2 * QC + 2 + jl) * TS];
    const float* nbr = &tile[(lr * QC + jl + dc + 2) * TS];

    double acc = 0.0;
    #pragma unroll 8
    for (int k = 0; k < 32; k++) {
        float2 cv = *(const float2*)(ctr + 2 * k);
        float2 nv = *(const float2*)(nbr + 2 * k);
        acc += (double)cv.x * (double)nv.x;       // c = 2k
        acc += (double)cv.y * (double)nv.y;       // c = 2k+1 (sequential order kept)
    }
    const int p = r * HW + jbase + jl;
    dots[(size_t)s * BP + b * PIX + p] = acc;     // plane-major: coalesced in jl
    if (s == 12) invn[(size_t)b * PIX + p] = 1.0 / sqrt(acc);
}

// ---------------------------------------------------------------------------
// Stage 2 (fused select + gather-conv), per (b, image row r). R24 body:
// R23 load/use-separated select + staging, R24 eager post-barrier hoists,
// R26 launch_bounds(256,2) (verified neutral, kept).
// ---------------------------------------------------------------------------
__global__ __launch_bounds__(256, 2) void fused_kernel(const unsigned short* __restrict__ xT,
                                                       const double* __restrict__ dots,
                                                       const double* __restrict__ invn,
                                                       const unsigned short* __restrict__ wbf,
                                                       float* __restrict__ out) {
    const int b = blockIdx.y;
    const int r = blockIdx.x;
    __shared__ unsigned short band[300 * LDB];
    __shared__ int qtab[9 * 64];
    const int t = threadIdx.x;

    const int wv = t >> 6, ln = t & 63;
    const int mrow = ln & 15, kq = ln >> 4;
    const int o = wv * 16 + mrow;

    if (t < 56) {
        const int jj = t;
        const int bp = b * PIX;
        const int p0 = r * HW + jj;
        const double* inb = invn + bp;

        // Phase A: pure loads into registers — all 50 issued before any use.
        double rawv[25], invv[25];
        #pragma unroll
        for (int s = 0; s < 25; s++) {
            int dr = s / 5 - 2, dc = s % 5 - 2;
            int qi = r + dr, qj = jj + dc;
            bool valid = qi >= 0 && qi < HW && qj >= 0 && qj < HW;
            int qc = valid ? qi * HW + qj : p0;   // clamped: always in-bounds
            rawv[s] = (s < 13) ? dots[(size_t)s * BP + bp + p0]
                               : dots[(size_t)(24 - s) * BP + bp + qc];
            invv[s] = inb[qc];
        }
        // Phase B: keys (invalid -> DBL_MAX mask; same values as R20).
        double k2[25];
        #pragma unroll
        for (int s = 0; s < 25; s++) {
            int dr = s / 5 - 2, dc = s % 5 - 2;
            int qi = r + dr, qj = jj + dc;
            bool valid = qi >= 0 && qi < HW && qj >= 0 && qj < HW;
            k2[s] = valid ? rawv[s] * invv[s] : DBL_MAX;
        }
        unsigned int used = 0;
        int bq[9];
        #pragma unroll
        for (int rr = 0; rr < 9; rr++) {
            double best = DBL_MAX; int bs = 0;
            #pragma unroll
            for (int s = 0; s < 25; s++) {
                bool ok = (((used >> s) & 1u) == 0u) && (k2[s] < best);
                if (ok) { best = k2[s]; bs = s; }
            }
            used |= (1u << bs);
            bq[rr] = (r + bs / 5 - 2) * HW + (jj + bs % 5 - 2);
        }
        #pragma unroll
        for (int a = 0; a < 8; a++) {
            #pragma unroll
            for (int c2 = 0; c2 < 8 - a; c2++) {
                int u = bq[c2], v = bq[c2 + 1];
                bq[c2] = u < v ? u : v; bq[c2 + 1] = u < v ? v : u;
            }
        }
        #pragma unroll
        for (int k = 0; k < 9; k++) {
            int q = bq[k], qi = q / HW, qj = q - qi * HW;
            qtab[k * 64 + jj] = ((qi - r + 2) * 60 + qj + 2) * LDB;
        }
    } else if (t < 64) {
        #pragma unroll
        for (int k = 0; k < 9; k++) qtab[k * 64 + t] = 0;   // tail dummy
    } else {
        // band staging: 2400 uint4 items over 192 threads = 12 or 13 each.
        // R23: compile-time unroll — all loads issued, then all ds_writes.
        const int l0 = t - 64;                    // 0..191
        uint4 v[13];
        #pragma unroll
        for (int it = 0; it < 13; it++) {
            int l = l0 + it * 192;
            v[it] = (uint4){0, 0, 0, 0};
            if (l < 2400) {
                int local = l >> 3, ch8 = l & 7;
                int lr = local / 60, col = local - lr * 60 - 2;
                int row = r - 2 + lr;
                if (row >= 0 && row < HW && col >= 0 && col < HW)
                    v[it] = *(const uint4*)(xT + ((size_t)b * PIX + row * HW + col) * CHN + ch8 * 8);
            }
        }
        #pragma unroll
        for (int it = 0; it < 13; it++) {
            int l = l0 + it * 192;
            if (l < 2400) {
                int local = l >> 3, ch8 = l & 7;
                *(uint4*)(&band[local * LDB + ch8 * 8]) = v[it];
            }
        }
    }
    __syncthreads();

    // R24: eager post-barrier hoists — A-fragments (18 x b128) and qtab
    // indices (36 x b32) batched before the tap loop; loop fully unrolled.
    bf16x8 afr[9][2];
    const unsigned short* wbase = wbf + (size_t)o * 9 * 64 + kq * 8;
    #pragma unroll
    for (int tap = 0; tap < 9; tap++) {
        afr[tap][0] = *(const bf16x8*)(wbase + tap * 64);
        afr[tap][1] = *(const bf16x8*)(wbase + tap * 64 + 32);
    }
    int qv[9][4];
    #pragma unroll
    for (int tap = 0; tap < 9; tap++) {
        #pragma unroll
        for (int nt = 0; nt < 4; nt++)
            qv[tap][nt] = qtab[tap * 64 + nt * 16 + mrow];
    }

    f32x4 oacc[4] = {{0,0,0,0},{0,0,0,0},{0,0,0,0},{0,0,0,0}};
    #pragma unroll
    for (int tap = 0; tap < 9; tap++) {
        #pragma unroll
        for (int nt = 0; nt < 4; nt++) {
            const unsigned short* bptr = &band[qv[tap][nt] + kq * 8];
            bf16x8 b0 = *(const bf16x8*)bptr;
            bf16x8 b1 = *(const bf16x8*)(bptr + 32);
            oacc[nt] = __builtin_amdgcn_mfma_f32_16x16x32_bf16(afr[tap][0], b0, oacc[nt], 0, 0, 0);
            oacc[nt] = __builtin_amdgcn_mfma_f32_16x16x32_bf16(afr[tap][1], b1, oacc[nt], 0, 0, 0);
        }
    }
    // C/D: col = lane&15 = p-within-tile, row = kq*4+rg = o-within-strip
    float* ob = out + ((size_t)b * 64 + wv * 16 + kq * 4) * PIX + r * HW;
    #pragma unroll
    for (int nt = 0; nt < 4; nt++) {
        int p = nt * 16 + mrow;
        if (p < HW) {
            #pragma unroll
            for (int rg = 0; rg < 4; rg++) ob[(size_t)rg * PIX + p] = oacc[nt][rg];
        }
    }
}

// ---------------------------------------------------------------------------
// Workspace layout (total ~6.1 MB):
//   dots : 13 * 25088 * 8 = 2,609,152 B @ 0          (plane-major [s][b][p])
//   invn : 25088 * 8      =   200,704 B @ 2,609,152
//   wbf  : 64*9*64 * 2    =    73,728 B @ 2,809,856
//   xT   : 8*3136*64 * 2  = 3,211,264 B @ 2,883,584
// ---------------------------------------------------------------------------
extern "C" void kernel_launch(void* const* d_in, const int* in_sizes, int n_in,
                              void* d_out, int out_size, void* d_ws, size_t ws_size,
                              hipStream_t stream) {
    const float* x = (const float*)d_in[0];
    const float* w = (const float*)d_in[1];
    float* out = (float*)d_out;
    char* ws = (char*)d_ws;
    double*         dots = (double*)ws;
    double*         invn = (double*)(ws + 2609152);
    unsigned short* wbf  = (unsigned short*)(ws + 2809856);
    unsigned short* xT   = (unsigned short*)(ws + 2883584);

    // 1792 blocks cover (b,r,quarter); 16 tail blocks pack wbf
    dots_kernel<<<1808, 256, 0, stream>>>(x, w, dots, invn, wbf, xT);
    fused_kernel<<<dim3(56, 8), 256, 0, stream>>>(xT, dots, invn, wbf, out);
}